// Round 19
// baseline (114.818 us; speedup 1.0000x reference)
//
#include <hip/hip_runtime.h>
#include <math.h>

#define NT 16384
#define D 4096
#define NE 128
#define BMT 32            // tokens per block
#define NSUP 16           // supers per K-half (128 floats each)
#define INV_T (1.0f / 0.07f)
#define TAU 2e-5f
#define FIXCAP 16384

typedef _Float16 h16;
typedef _Float16 h8 __attribute__((ext_vector_type(8)));
typedef _Float16 h4 __attribute__((ext_vector_type(4)));
typedef float f4 __attribute__((ext_vector_type(4)));
typedef float f16v __attribute__((ext_vector_type(16)));

// ---- static device scratch (fully rewritten each call) ----
__device__ float g_wgn[NE * D];          // normalized W fp32 (fixup)
// W hi packed: [chunk C=k>>5][m][g][oct][e5][8 h16] -> 8KB per chunk
__device__ __align__(16) h16 g_wpk[NE * D];
__device__ int   g_tte[NT];
__device__ int   g_cnt;
__device__ int   g_flag[FIXCAP];
__device__ float g_cand[FIXCAP][NE];
__device__ float g_me[NT / BMT][NE];
__device__ int   g_hist[256][NE];
__device__ int   g_pos[256][NE];

#define GLL(gp, lp) __builtin_amdgcn_global_load_lds( \
    (const __attribute__((address_space(1))) void*)(gp), \
    (__attribute__((address_space(3))) void*)(lp), 16, 0, 0)
#define SB __builtin_amdgcn_sched_barrier(0)

// ---------------- kernel 1: normalize W + fp16 hi split + pack + hist zero ----
__global__ __launch_bounds__(256) void k_prep(const float* __restrict__ wg) {
    int e = blockIdx.x;
    int tid = threadIdx.x;
    if (e == 0 && tid == 0) g_cnt = 0;
    g_hist[e * 2 + (tid >> 7)][tid & 127] = 0;
    const f4* row = (const f4*)(wg + (size_t)e * D);
    float ss = 0.f;
    f4 v[4];
    #pragma unroll
    for (int c = 0; c < 4; c++) {
        v[c] = row[tid + 256 * c];
        ss += v[c][0]*v[c][0] + v[c][1]*v[c][1] + v[c][2]*v[c][2] + v[c][3]*v[c][3];
    }
    __shared__ float red[4];
    #pragma unroll
    for (int o = 32; o > 0; o >>= 1) ss += __shfl_xor(ss, o, 64);
    if ((tid & 63) == 0) red[tid >> 6] = ss;
    __syncthreads();
    float den = fmaxf(sqrtf(red[0] + red[1] + red[2] + red[3]), 1e-4f);
    int g = e >> 5, e5 = e & 31;
    #pragma unroll
    for (int cc2 = 0; cc2 < 4; cc2++) {
        int k0 = (tid + 256 * cc2) * 4;
        f4 wn;
        h4 hi;
        #pragma unroll
        for (int k = 0; k < 4; k++) {
            wn[k] = v[cc2][k] / den;
            hi[k] = (h16)wn[k];
        }
        *(f4*)(g_wgn + (size_t)e * D + k0) = wn;
        // k -> C=k>>5, oct=(k>>4)&1, m=(k>>3)&1, j=k&7
        int C = k0 >> 5, oct = (k0 >> 4) & 1, m = (k0 >> 3) & 1;
        size_t off = (size_t)C * 8192 + (size_t)m * 4096
                   + (size_t)g * 1024 + (size_t)oct * 512 + (size_t)e5 * 16
                   + (size_t)(k0 & 7) * 2;
        *(h4*)((char*)g_wpk + off) = hi;
    }
}

// ---------------- kernel 2: fused fp16x2 32x32x16 GEMM + epilogue -------------
// grid 512 (2 blk/CU), 256 thr = 4 waves. Wave (kh=w>>1, eh=w&1): 32 tokens x
// 64 experts x K-half. eh-waves of a kh-group SHARE one x buffer -> 512 B/row
// GLL bursts (one instr = 2 rows x 512 B contiguous).
// r17/r18 bug: STAGE(S+2) overwrites the shared buffer BEFORE the barrier ->
// partner wave still reading rows 16-31 when GLL data lands (cross-wave WAR).
// Fix: stage strictly AFTER the end-of-super barrier (all readers done).
__global__ __launch_bounds__(256, 2) void k_gemm(const float* __restrict__ x) {
    __shared__ __align__(16) char ldsb[65536];   // 2 khgroups x 2 bufs x 16KB
    __shared__ float ssqr[2][32];
    __shared__ int hh[NE];

    const int tid = threadIdx.x;
    const int t0 = blockIdx.x * BMT;
    const int w = tid >> 6, l = tid & 63;
    const int kh = w >> 1, eh = w & 1;
    const int e5 = l & 31, oct = l >> 5;

    if (tid < NE) hh[tid] = 0;

    // W: expert groups eh*2, eh*2+1; local chunk c -> global C = kh*64 + c
    const char* wbase = (const char*)g_wpk + (size_t)(kh * 64) * 8192
                        + (size_t)eh * 2048 + (size_t)oct * 512 + (size_t)e5 * 16;
    // x staging source base (row/slot/swizzle added per GLL)
    const char* xc = (const char*)x + (size_t)t0 * 16384 + (size_t)kh * 8192;
    char* kbuf = ldsb + kh * 32768;

    f16v acc[2];
    acc[0] = (f16v)0.0f; acc[1] = (f16v)0.0f;
    float sq0 = 0.f, sq1 = 0.f, sq2 = 0.f, sq3 = 0.f;
    h8 ah[2], al[2], bA[4], bB[4];

#define LOADW(B_, c) do { _Pragma("unroll") for (int j = 0; j < 4; j++) \
        B_[j] = *(const h8*)(wbase + (size_t)(c) * 8192 + (j >> 1) * 4096 + (j & 1) * 1024); } while (0)

// stage super S of this kh-group: wave eh covers rows eh*16..+15, 8 GLL of
// 2 rows x 512 B; LDS slot j of row r holds global slot j^r (source pre-swz)
#define STAGE(S) do { \
        char* d_ = kbuf + (((S) & 1) << 14) + (eh << 13); \
        _Pragma("unroll") for (int i_ = 0; i_ < 8; i_++) { \
            int rl_ = eh * 16 + 2 * i_ + (l >> 5); \
            const char* s_ = xc + (size_t)rl_ * 16384 + (size_t)(S) * 512 \
                             + (size_t)(((l & 31) ^ rl_) << 4); \
            GLL(s_, d_ + i_ * 1024); } } while (0)

// chunk CH (0..3) of super S: lane reads row e5, slots CH*8+oct*4+q (^e5 swz)
#define CHUNK(S, CH, B_) do { \
        const char* b_ = kbuf + (((S) & 1) << 14) + e5 * 512; \
        f4 xr[4]; \
        _Pragma("unroll") for (int q = 0; q < 4; q++) \
            xr[q] = *(const f4*)(b_ + (((((CH) * 8 + oct * 4) | q) ^ e5) << 4)); \
        _Pragma("unroll") for (int q = 0; q < 4; q++) { \
            _Pragma("unroll") for (int e2 = 0; e2 < 4; e2++) { \
                float f_ = xr[q][e2]; \
                if (q == 0) sq0 = fmaf(f_, f_, sq0); \
                else if (q == 1) sq1 = fmaf(f_, f_, sq1); \
                else if (q == 2) sq2 = fmaf(f_, f_, sq2); \
                else sq3 = fmaf(f_, f_, sq3); \
                h16 h_ = (h16)f_; \
                ah[q >> 1][(q & 1) * 4 + e2] = h_; \
                al[q >> 1][(q & 1) * 4 + e2] = (h16)(f_ - (float)h_); } } \
        _Pragma("unroll") for (int m = 0; m < 2; m++) \
            _Pragma("unroll") for (int jg = 0; jg < 2; jg++) { \
                acc[jg] = __builtin_amdgcn_mfma_f32_32x32x16_f16(ah[m], B_[m * 2 + jg], acc[jg], 0, 0, 0); \
                acc[jg] = __builtin_amdgcn_mfma_f32_32x32x16_f16(al[m], B_[m * 2 + jg], acc[jg], 0, 0, 0); } \
    } while (0)

// Order per super: chunks -> vmcnt(16) [drains STAGE(S+1): FIFO = G(S+1)(8
// oldest) + 16 W(S)] -> barrier [all waves done READING buf (S&1)] ->
// STAGE(S+2) into buf (S&1). Regions SB-pinned so the count is exact.
#define SUPER(S, STG, LDL, WAIT) do { \
        LOADW(bB, 4 * (S) + 1); SB; \
        CHUNK(S, 0, bA); SB; \
        LOADW(bA, 4 * (S) + 2); SB; \
        CHUNK(S, 1, bB); SB; \
        LOADW(bB, 4 * (S) + 3); SB; \
        CHUNK(S, 2, bA); SB; \
        if (LDL) LOADW(bA, 4 * (S) + 4); \
        SB; \
        CHUNK(S, 3, bB); SB; \
        if (WAIT) { \
            asm volatile("s_waitcnt vmcnt(16)" ::: "memory"); \
            __builtin_amdgcn_s_barrier(); SB; \
        } \
        if (STG) STAGE((S) + 2); \
        SB; } while (0)

    // prologue: W chunk 0 first (FIFO), then supers 0,1; drain W0 + STAGE(0)
    LOADW(bA, 0); SB;
    STAGE(0); SB;
    STAGE(1); SB;
    asm volatile("s_waitcnt vmcnt(8)" ::: "memory");
    __builtin_amdgcn_s_barrier(); SB;

    SUPER(0, 1, 1, 1);
    #pragma unroll 1
    for (int s = 1; s <= 13; s++) SUPER(s, 1, 1, 1);
    SUPER(14, 0, 1, 1);
    SUPER(15, 0, 0, 0);

    // per-token |x|^2 for this K-half (both eh-waves compute identically)
    float ssq = (sq0 + sq1) + (sq2 + sq3);
    ssq += __shfl_xor(ssq, 32, 64);
    if (eh == 0 && l < 32) ssqr[kh][l] = ssq;

    // cross-kh reduction: kh1 deposits, kh0 adds -> gates[32][128] (aliases ldsb)
    typedef float grow[128];
    grow* gates = (grow*)ldsb;

    __syncthreads();
    if (kh == 1) {
        #pragma unroll
        for (int jg = 0; jg < 2; jg++)
            #pragma unroll
            for (int q = 0; q < 16; q++)
                gates[(q & 3) + 8 * (q >> 2) + 4 * oct][eh * 64 + jg * 32 + e5] = acc[jg][q];
    }
    __syncthreads();
    if (kh == 0) {
        #pragma unroll
        for (int jg = 0; jg < 2; jg++)
            #pragma unroll
            for (int q = 0; q < 16; q++) {
                int r = (q & 3) + 8 * (q >> 2) + 4 * oct;
                gates[r][eh * 64 + jg * 32 + e5] += acc[jg][q];
            }
    }
    __syncthreads();

    // ---- epilogue: 8 threads per token, 16 experts each ----
    const int tl = tid >> 3, g8 = tid & 7, e0 = g8 * 16;
    float n2 = ssqr[0][tl] + ssqr[1][tl];
    float scl = 1.0f / fmaxf(sqrtf(n2), 1e-4f);
    float v[16];
    #pragma unroll
    for (int k = 0; k < 16; k += 4) *(f4*)&v[k] = *(const f4*)&gates[tl][e0 + k];

    float m1 = -1e30f, m2 = -1e30f;
    int a1 = e0;
    #pragma unroll
    for (int k = 0; k < 16; k++) {
        float cv = v[k] * scl;
        v[k] = cv;
        if (cv > m1) { m2 = m1; m1 = cv; a1 = e0 + k; }
        else if (cv > m2) m2 = cv;
    }
    #pragma unroll
    for (int o = 1; o < 8; o <<= 1) {
        float m1o = __shfl_xor(m1, o, 64);
        int   a1o = __shfl_xor(a1, o, 64);
        float m2o = __shfl_xor(m2, o, 64);
        m2 = fmaxf(fmaxf(m2, m2o), fminf(m1, m1o));
        if (m1o > m1 || (m1o == m1 && a1o < a1)) { m1 = m1o; a1 = a1o; }
    }
    const int tg = t0 + tl;
    if (g8 == 0) {
        g_tte[tg] = a1;
        atomicAdd(&hh[a1], 1);
    }
    if (m1 - m2 < TAU) {
        int ix = 0;
        if (g8 == 0) ix = atomicAdd(&g_cnt, 1);
        ix = __shfl(ix, l & ~7, 64);
        if (ix < FIXCAP) {
            if (g8 == 0) g_flag[ix] = tg;
            #pragma unroll
            for (int k = 0; k < 16; k += 4) {
                f4 t4;
                t4[0] = v[k]; t4[1] = v[k + 1]; t4[2] = v[k + 2]; t4[3] = v[k + 3];
                *(f4*)&g_cand[ix][e0 + k] = t4;
            }
        }
    }

    // softmax(cos/0.07); in-place store (each thread owns its 16-col span)
    float ssum = 0.f;
    #pragma unroll
    for (int k = 0; k < 16; k++) {
        float ex = __expf((v[k] - m1) * INV_T);
        v[k] = ex;
        ssum += ex;
    }
    ssum += __shfl_xor(ssum, 1, 64);
    ssum += __shfl_xor(ssum, 2, 64);
    ssum += __shfl_xor(ssum, 4, 64);
    float inv = 1.0f / ssum;
    #pragma unroll
    for (int k = 0; k < 16; k += 4) {
        f4 t4;
        t4[0] = v[k] * inv; t4[1] = v[k + 1] * inv;
        t4[2] = v[k + 2] * inv; t4[3] = v[k + 3] * inv;
        *(f4*)&gates[tl][e0 + k] = t4;
    }
    __syncthreads();
    if (tid < NE) {
        float s = 0.f;
        #pragma unroll 8
        for (int r = 0; r < 32; r++) s += gates[r][tid];
        g_me[blockIdx.x][tid] = s;
        atomicAdd(&g_hist[blockIdx.x >> 1][tid], hh[tid]);
    }

#undef LOADW
#undef STAGE
#undef CHUNK
#undef SUPER
}

// ---------------- kernel 3: exact fp32 recheck of near-tie tokens -------------
__global__ __launch_bounds__(64) void k_fix(const float* __restrict__ x) {
    int n = g_cnt;
    if (n > FIXCAP) n = FIXCAP;
    const int l = threadIdx.x;
    for (int i = blockIdx.x; i < n; i += gridDim.x) {
        int t = g_flag[i];
        float c0 = g_cand[i][l], c1 = g_cand[i][l + 64];
        float m = fmaxf(c0, c1);
        #pragma unroll
        for (int o = 1; o < 64; o <<= 1) m = fmaxf(m, __shfl_xor(m, o, 64));
        float thr = m - TAU;
        unsigned long long b0 = __ballot(c0 >= thr);
        unsigned long long b1 = __ballot(c1 >= thr);

        const float* xr = x + (size_t)t * D;
        float bm = -1e30f;
        int ba = 0;
        #pragma unroll 1
        for (int half = 0; half < 2; half++) {
            unsigned long long b = half ? b1 : b0;
            while (b) {
                int e = (__ffsll((long long)b) - 1) + half * 64;
                b &= b - 1;
                const float* wr = g_wgn + (size_t)e * D;
                float s = 0.f;
                #pragma unroll 4
                for (int c = 0; c < 16; c++) {
                    f4 xv = *(const f4*)(xr + c * 256 + l * 4);
                    f4 wv = *(const f4*)(wr + c * 256 + l * 4);
                    s = fmaf(xv[0], wv[0], s);
                    s = fmaf(xv[1], wv[1], s);
                    s = fmaf(xv[2], wv[2], s);
                    s = fmaf(xv[3], wv[3], s);
                }
                #pragma unroll
                for (int o = 1; o < 64; o <<= 1) s += __shfl_xor(s, o, 64);
                if (s > bm) { bm = s; ba = e; }
            }
        }
        if (l == 0) {
            int old = g_tte[t];
            if (ba != old) {
                g_tte[t] = ba;
                atomicSub(&g_hist[t >> 6][old], 1);
                atomicAdd(&g_hist[t >> 6][ba], 1);
            }
        }
    }
}

// ---------------- kernel 4: scans + l_aux + splits ----------------------------
__global__ __launch_bounds__(128) void k_scan(float* __restrict__ out) {
    __shared__ int total[NE];
    __shared__ float me[NE];
    int e = threadIdx.x;
    int run = 0;
    #pragma unroll 8
    for (int c = 0; c < 256; c++) run += g_hist[c][e];
    total[e] = run;
    __syncthreads();
    int off = 0;
    for (int i = 0; i < e; i++) off += total[i];
    int p = off;
    for (int c = 0; c < 256; c++) { g_pos[c][e] = p; p += g_hist[c][e]; }
    float s = 0.f;
    #pragma unroll 8
    for (int b = 0; b < NT / BMT; b++) s += g_me[b][e];
    me[e] = s;
    __syncthreads();
    if (e == 0) {
        float acc = 0.f;
        for (int i = 0; i < NE; i++)
            acc += me[i] * ((float)total[i] * (1.0f / 16384.0f) + 1e-6f);
        out[0] = acc * 128.0f;   // l_aux
    }
    out[1 + NT + e]      = (float)total[e];   // input_splits
    out[1 + NT + NE + e] = (float)total[e];   // output_splits
}

// ---------------- kernel 5: stable placement (counting sort) ------------------
__global__ __launch_bounds__(64) void k_place(float* __restrict__ out) {
    __shared__ int arr[64];
    int tid = threadIdx.x;
    int c = blockIdx.x;
    int t = c * 64 + tid;
    int e = g_tte[t];
    arr[tid] = e;
    __syncthreads();
    int rank = 0;
    for (int j = 0; j < tid; j++) rank += (arr[j] == e) ? 1 : 0;
    out[1 + g_pos[c][e] + rank] = (float)t;
}

// ---------------- launcher ----------------------------------------------------
extern "C" void kernel_launch(void* const* d_in, const int* in_sizes, int n_in,
                              void* d_out, int out_size, void* d_ws, size_t ws_size,
                              hipStream_t stream) {
    const float* x  = (const float*)d_in[0];
    const float* wg = (const float*)d_in[1];
    // d_in[2] = gating_t: sigmoid(x/temp) is monotonic -> argmax unaffected
    float* out = (float*)d_out;

    k_prep<<<NE, 256, 0, stream>>>(wg);
    k_gemm<<<NT / BMT, 256, 0, stream>>>(x);
    k_fix<<<2048, 64, 0, stream>>>(x);
    k_scan<<<1, 128, 0, stream>>>(out);
    k_place<<<256, 64, 0, stream>>>(out);
}

// Round 20
// 87.983 us; speedup vs baseline: 1.3050x; 1.3050x over previous
//
#include <hip/hip_runtime.h>
#include <math.h>

#define NT 16384
#define D 4096
#define NE 128
#define BMT 32            // tokens per block
#define NSUP 16           // supers per K-quarter (64 floats each)
#define NCHT 128          // total 32-k chunks
#define INV_T (1.0f / 0.07f)
#define TAU 2e-5f
#define FIXCAP 16384

typedef _Float16 h16;
typedef _Float16 h8 __attribute__((ext_vector_type(8)));
typedef _Float16 h4 __attribute__((ext_vector_type(4)));
typedef float f4 __attribute__((ext_vector_type(4)));
typedef float f16v __attribute__((ext_vector_type(16)));

// ---- static device scratch (fully rewritten each call) ----
__device__ float g_wgn[NE * D];          // normalized W fp32 (fixup)
// W hi packed: [slice*32+c][m][g][oct][e5][8 h16] -> 8KB per chunk
__device__ __align__(16) h16 g_wpk[NE * D];
__device__ int   g_tte[NT];
__device__ int   g_cnt;
__device__ int   g_flag[FIXCAP];
__device__ float g_cand[FIXCAP][NE];
__device__ float g_me[NT / BMT][NE];
__device__ int   g_hist[256][NE];
__device__ int   g_pos[256][NE];

#define GLL(gp, lp) __builtin_amdgcn_global_load_lds( \
    (const __attribute__((address_space(1))) void*)(gp), \
    (__attribute__((address_space(3))) void*)(lp), 16, 0, 0)
#define SB __builtin_amdgcn_sched_barrier(0)

// ---------------- kernel 1: normalize W + fp16 hi split + pack + hist zero ----
__global__ __launch_bounds__(256) void k_prep(const float* __restrict__ wg) {
    int e = blockIdx.x;
    int tid = threadIdx.x;
    if (e == 0 && tid == 0) g_cnt = 0;
    g_hist[e * 2 + (tid >> 7)][tid & 127] = 0;
    const f4* row = (const f4*)(wg + (size_t)e * D);
    float ss = 0.f;
    f4 v[4];
    #pragma unroll
    for (int c = 0; c < 4; c++) {
        v[c] = row[tid + 256 * c];
        ss += v[c][0]*v[c][0] + v[c][1]*v[c][1] + v[c][2]*v[c][2] + v[c][3]*v[c][3];
    }
    __shared__ float red[4];
    #pragma unroll
    for (int o = 32; o > 0; o >>= 1) ss += __shfl_xor(ss, o, 64);
    if ((tid & 63) == 0) red[tid >> 6] = ss;
    __syncthreads();
    float den = fmaxf(sqrtf(red[0] + red[1] + red[2] + red[3]), 1e-4f);
    int g = e >> 5, e5 = e & 31;
    #pragma unroll
    for (int cc2 = 0; cc2 < 4; cc2++) {
        int k0 = (tid + 256 * cc2) * 4;
        f4 wn;
        h4 hi;
        #pragma unroll
        for (int k = 0; k < 4; k++) {
            wn[k] = v[cc2][k] / den;
            hi[k] = (h16)wn[k];
        }
        *(f4*)(g_wgn + (size_t)e * D + k0) = wn;
        // k -> slice=k>>10, cc=(k>>5)&31, oct=(k>>4)&1, m=(k>>3)&1, j=k&7
        int slice = k0 >> 10, cc = (k0 >> 5) & 31;
        int oct = (k0 >> 4) & 1, m = (k0 >> 3) & 1;
        size_t off = (size_t)(slice * 32 + cc) * 8192 + (size_t)m * 4096
                   + (size_t)g * 1024 + (size_t)oct * 512 + (size_t)e5 * 16
                   + (size_t)(k0 & 7) * 2;
        *(h4*)((char*)g_wpk + off) = hi;
    }
}

// ---------------- kernel 2: fused fp16x2 32x32x16 GEMM + epilogue -------------
// grid 512 (2 blk/CU), 256 thr = 4 waves; wave w owns K-quarter [w*1024,+1024).
// x staged via global_load_lds: ONE instruction = ONE row's 1KB contiguous span
// (DRAM page opened once per KB, vs 128B visits before). Wave-PRIVATE 2x8KB
// double buffer -> no block barriers in the K-loop; 2-deep staging with FIFO-
// audited counted vmcnt; source-side XOR slot swizzle (read side applies same
// involution); A/B k-bijection absorbed into k_prep's W pack.
// (Measured-best r16 structure, byte-identical.)
__global__ __launch_bounds__(256, 2) void k_gemm(const float* __restrict__ x) {
    __shared__ __align__(16) char ldsb[65536];   // 4 waves x 2 bufs x 8KB
    __shared__ float ssqr[4][32];
    __shared__ int hh[NE];

    const int tid = threadIdx.x;
    const int t0 = blockIdx.x * BMT;
    const int w = tid >> 6, l = tid & 63;
    const int e5 = l & 31, oct = l >> 5;
    const int r256 = (l & 31) * 256, rx = l & 7, oct4 = oct * 4;

    const char* wbase = (const char*)g_wpk + (size_t)w * 32 * 8192
                        + (size_t)oct * 512 + (size_t)e5 * 16;
    // GLL source bases (lane l handles row (l>>4) of each 4-row group, slot
    // pre-swizzled so LDS slot s holds global slot s ^ (row&7))
    const char* xc = (const char*)x;
    const char* srcE = xc + ((size_t)(t0 + (l >> 4))) * 16384 + (size_t)w * 4096
                       + (size_t)(((l & 15) ^ (l >> 4)) << 4);
    const char* srcO = xc + ((size_t)(t0 + (l >> 4))) * 16384 + (size_t)w * 4096
                       + (size_t)(((l & 15) ^ (4 | (l >> 4))) << 4);

    if (tid < NE) hh[tid] = 0;

    f16v acc[4];
    acc[0] = (f16v)0.0f; acc[1] = (f16v)0.0f;
    acc[2] = (f16v)0.0f; acc[3] = (f16v)0.0f;
    float sq0 = 0.f, sq1 = 0.f, sq2 = 0.f, sq3 = 0.f;
    f4 xr[4];
    h8 ah[2], al[2], bA[8], bB[8];

#define STAGE(S) do { \
        char* d_ = ldsb + w * 16384 + ((S) & 1) * 8192; \
        _Pragma("unroll") for (int i_ = 0; i_ < 8; i_++) \
            GLL((i_ & 1 ? srcO : srcE) + (size_t)i_ * 65536 + (size_t)(S) * 256, \
                d_ + i_ * 1024); } while (0)

#define LOADW(B_, c) do { _Pragma("unroll") for (int j = 0; j < 8; j++) \
        B_[j] = *(const h8*)(wbase + (size_t)(c) * 8192 + (j >> 2) * 4096 + (j & 3) * 1024); } while (0)

#define CHUNK(S, CH, B_) do { \
        const char* b_ = ldsb + w * 16384 + ((S) & 1) * 8192 + r256; \
        const int w0_ = (CH) * 8 + oct4; \
        xr[0] = *(const f4*)(b_ + (((w0_ | 0) ^ rx) << 4)); \
        xr[1] = *(const f4*)(b_ + (((w0_ | 1) ^ rx) << 4)); \
        xr[2] = *(const f4*)(b_ + (((w0_ | 2) ^ rx) << 4)); \
        xr[3] = *(const f4*)(b_ + (((w0_ | 3) ^ rx) << 4)); \
        _Pragma("unroll") for (int q = 0; q < 4; q++) { \
            _Pragma("unroll") for (int e2 = 0; e2 < 4; e2++) { \
                float f_ = xr[q][e2]; \
                if (q == 0) sq0 = fmaf(f_, f_, sq0); \
                else if (q == 1) sq1 = fmaf(f_, f_, sq1); \
                else if (q == 2) sq2 = fmaf(f_, f_, sq2); \
                else sq3 = fmaf(f_, f_, sq3); \
                h16 h_ = (h16)f_; \
                ah[q >> 1][(q & 1) * 4 + e2] = h_; \
                al[q >> 1][(q & 1) * 4 + e2] = (h16)(f_ - (float)h_); } } \
        _Pragma("unroll") for (int m = 0; m < 2; m++) \
            _Pragma("unroll") for (int g = 0; g < 4; g++) { \
                acc[g] = __builtin_amdgcn_mfma_f32_32x32x16_f16(ah[m], B_[m * 4 + g], acc[g], 0, 0, 0); \
                acc[g] = __builtin_amdgcn_mfma_f32_32x32x16_f16(al[m], B_[m * 4 + g], acc[g], 0, 0, 0); } \
    } while (0)

// per super: [bB load][manual vmcnt: buf(S) staged][chunk 2S w/ bA][bA load next]
//            [chunk 2S+1 w/ bB][stage super S+2]   (regions pinned by SB)
#define SUPER(S, VN, LDA, STG) do { \
        LOADW(bB, 2 * (S) + 1); \
        SB; asm volatile("s_waitcnt vmcnt(" #VN ")" ::: "memory"); SB; \
        CHUNK(S, 0, bA); \
        SB; \
        if (LDA) LOADW(bA, 2 * (S) + 2); \
        SB; \
        CHUNK(S, 1, bB); \
        SB; \
        if (STG) STAGE((S) + 2); \
        SB; } while (0)

    // prologue: stage supers 0,1 (16 GLL), preload W chunk 0
    STAGE(0);
    STAGE(1);
    LOADW(bA, 0);
    SB;

    SUPER(0, 24, 1, 1);
    SUPER(1, 40, 1, 1);
    #pragma unroll 1
    for (int s = 2; s <= 13; s++) SUPER(s, 32, 1, 1);
    SUPER(14, 32, 1, 0);
    SUPER(15, 24, 0, 0);

    // per-token |x|^2 for this K-quarter (oct halves hold disjoint k)
    float ssq = (sq0 + sq1) + (sq2 + sq3);
    ssq += __shfl_xor(ssq, 32, 64);
    if (l < 32) ssqr[w][l] = ssq;

    // deterministic cross-wave (K-slice) reduction via LDS (aliases x buffers)
    typedef float redt[32][128];
    redt* red = (redt*)ldsb;

#define ACCST(H) do { _Pragma("unroll") for (int g = 0; g < 4; g++) \
        _Pragma("unroll") for (int q = 0; q < 16; q++) \
            red[H][(q & 3) + 8 * (q >> 2) + 4 * oct][g * 32 + e5] = acc[g][q]; } while (0)
#define ACCADD(H) do { _Pragma("unroll") for (int g = 0; g < 4; g++) \
        _Pragma("unroll") for (int q = 0; q < 16; q++) \
            acc[g][q] += red[H][(q & 3) + 8 * (q >> 2) + 4 * oct][g * 32 + e5]; } while (0)

    __syncthreads();
    if (w == 1) ACCST(0);
    if (w == 3) ACCST(1);
    __syncthreads();
    if (w == 0) ACCADD(0);
    if (w == 2) ACCADD(1);
    __syncthreads();
    if (w == 2) ACCST(1);
    __syncthreads();
    if (w == 0) { ACCADD(1); ACCST(0); }   // full raw dots -> red[0]
    __syncthreads();

    // ---- epilogue: 8 threads per token, 16 experts each ----
    const int tl = tid >> 3, g8 = tid & 7, e0 = g8 * 16;
    float n2 = ssqr[0][tl] + ssqr[1][tl] + ssqr[2][tl] + ssqr[3][tl];
    float scl = 1.0f / fmaxf(sqrtf(n2), 1e-4f);
    float v[16];
    #pragma unroll
    for (int k = 0; k < 16; k += 4) *(f4*)&v[k] = *(const f4*)&red[0][tl][e0 + k];

    float m1 = -1e30f, m2 = -1e30f;
    int a1 = e0;
    #pragma unroll
    for (int k = 0; k < 16; k++) {
        float cv = v[k] * scl;
        v[k] = cv;
        if (cv > m1) { m2 = m1; m1 = cv; a1 = e0 + k; }
        else if (cv > m2) m2 = cv;
    }
    #pragma unroll
    for (int o = 1; o < 8; o <<= 1) {
        float m1o = __shfl_xor(m1, o, 64);
        int   a1o = __shfl_xor(a1, o, 64);
        float m2o = __shfl_xor(m2, o, 64);
        m2 = fmaxf(fmaxf(m2, m2o), fminf(m1, m1o));
        if (m1o > m1 || (m1o == m1 && a1o < a1)) { m1 = m1o; a1 = a1o; }
    }
    const int tg = t0 + tl;
    if (g8 == 0) {
        g_tte[tg] = a1;
        atomicAdd(&hh[a1], 1);
    }
    if (m1 - m2 < TAU) {
        int ix = 0;
        if (g8 == 0) ix = atomicAdd(&g_cnt, 1);
        ix = __shfl(ix, l & ~7, 64);
        if (ix < FIXCAP) {
            if (g8 == 0) g_flag[ix] = tg;
            #pragma unroll
            for (int k = 0; k < 16; k += 4) {
                f4 t4;
                t4[0] = v[k]; t4[1] = v[k + 1]; t4[2] = v[k + 2]; t4[3] = v[k + 3];
                *(f4*)&g_cand[ix][e0 + k] = t4;
            }
        }
    }

    // softmax(cos/0.07)
    float ssum = 0.f;
    #pragma unroll
    for (int k = 0; k < 16; k++) {
        float ex = __expf((v[k] - m1) * INV_T);
        v[k] = ex;
        ssum += ex;
    }
    ssum += __shfl_xor(ssum, 1, 64);
    ssum += __shfl_xor(ssum, 2, 64);
    ssum += __shfl_xor(ssum, 4, 64);
    float inv = 1.0f / ssum;
    #pragma unroll
    for (int k = 0; k < 16; k += 4) {
        f4 t4;
        t4[0] = v[k] * inv; t4[1] = v[k + 1] * inv;
        t4[2] = v[k + 2] * inv; t4[3] = v[k + 3] * inv;
        *(f4*)&red[1][tl][e0 + k] = t4;
    }
    __syncthreads();
    if (tid < NE) {
        float s = 0.f;
        #pragma unroll 8
        for (int r = 0; r < 32; r++) s += red[1][r][tid];
        g_me[blockIdx.x][tid] = s;
        atomicAdd(&g_hist[blockIdx.x >> 1][tid], hh[tid]);
    }

#undef STAGE
#undef LOADW
#undef CHUNK
#undef SUPER
#undef ACCST
#undef ACCADD
}

// ---------------- kernel 3: exact fp32 recheck of near-tie tokens -------------
__global__ __launch_bounds__(64) void k_fix(const float* __restrict__ x) {
    int n = g_cnt;
    if (n > FIXCAP) n = FIXCAP;
    const int l = threadIdx.x;
    for (int i = blockIdx.x; i < n; i += gridDim.x) {
        int t = g_flag[i];
        float c0 = g_cand[i][l], c1 = g_cand[i][l + 64];
        float m = fmaxf(c0, c1);
        #pragma unroll
        for (int o = 1; o < 64; o <<= 1) m = fmaxf(m, __shfl_xor(m, o, 64));
        float thr = m - TAU;
        unsigned long long b0 = __ballot(c0 >= thr);
        unsigned long long b1 = __ballot(c1 >= thr);

        const float* xr = x + (size_t)t * D;
        float bm = -1e30f;
        int ba = 0;
        #pragma unroll 1
        for (int half = 0; half < 2; half++) {
            unsigned long long b = half ? b1 : b0;
            while (b) {
                int e = (__ffsll((long long)b) - 1) + half * 64;
                b &= b - 1;
                const float* wr = g_wgn + (size_t)e * D;
                float s = 0.f;
                #pragma unroll 4
                for (int c = 0; c < 16; c++) {
                    f4 xv = *(const f4*)(xr + c * 256 + l * 4);
                    f4 wv = *(const f4*)(wr + c * 256 + l * 4);
                    s = fmaf(xv[0], wv[0], s);
                    s = fmaf(xv[1], wv[1], s);
                    s = fmaf(xv[2], wv[2], s);
                    s = fmaf(xv[3], wv[3], s);
                }
                #pragma unroll
                for (int o = 1; o < 64; o <<= 1) s += __shfl_xor(s, o, 64);
                if (s > bm) { bm = s; ba = e; }
            }
        }
        if (l == 0) {
            int old = g_tte[t];
            if (ba != old) {
                g_tte[t] = ba;
                atomicSub(&g_hist[t >> 6][old], 1);
                atomicAdd(&g_hist[t >> 6][ba], 1);
            }
        }
    }
}

// ---------------- kernel 4: scans + l_aux + splits (4-way parallel) -----------
// 512 threads: expert e = tid&127, slice p = tid>>7. Each slice sums 64 hist
// chunks + 128 me rows; LDS-reduce; g_pos emission split 4-way via slice-local
// prefix sums. (Was 1x128 threads with 768 serial loads/thread -> latency-bound.)
__global__ __launch_bounds__(512) void k_scan(float* __restrict__ out) {
    __shared__ int part[NE][4];
    __shared__ float mep[NE][4];
    __shared__ int total[NE];
    __shared__ float me[NE];
    int tid = threadIdx.x;
    int e = tid & 127, p = tid >> 7;

    int run = 0;
    #pragma unroll 8
    for (int c = p * 64; c < p * 64 + 64; c++) run += g_hist[c][e];
    part[e][p] = run;
    float s = 0.f;
    #pragma unroll 8
    for (int b = p * 128; b < p * 128 + 128; b++) s += g_me[b][e];
    mep[e][p] = s;
    __syncthreads();
    if (p == 0) {
        total[e] = part[e][0] + part[e][1] + part[e][2] + part[e][3];
        me[e]    = mep[e][0] + mep[e][1] + mep[e][2] + mep[e][3];
    }
    __syncthreads();

    // exclusive scan over experts (LDS-only, serial per thread) + slice offset
    int off = 0;
    for (int i = 0; i < e; i++) off += total[i];
    for (int q = 0; q < p; q++) off += part[e][q];
    int pp = off;
    for (int c = p * 64; c < p * 64 + 64; c++) { g_pos[c][e] = pp; pp += g_hist[c][e]; }

    if (tid == 0) {
        float acc = 0.f;
        for (int i = 0; i < NE; i++)
            acc += me[i] * ((float)total[i] * (1.0f / 16384.0f) + 1e-6f);
        out[0] = acc * 128.0f;   // l_aux
    }
    if (p == 0) {
        out[1 + NT + e]      = (float)total[e];   // input_splits
        out[1 + NT + NE + e] = (float)total[e];   // output_splits
    }
}

// ---------------- kernel 5: stable placement (counting sort) ------------------
__global__ __launch_bounds__(64) void k_place(float* __restrict__ out) {
    __shared__ int arr[64];
    int tid = threadIdx.x;
    int c = blockIdx.x;
    int t = c * 64 + tid;
    int e = g_tte[t];
    arr[tid] = e;
    __syncthreads();
    int rank = 0;
    for (int j = 0; j < tid; j++) rank += (arr[j] == e) ? 1 : 0;
    out[1 + g_pos[c][e] + rank] = (float)t;
}

// ---------------- launcher ----------------------------------------------------
extern "C" void kernel_launch(void* const* d_in, const int* in_sizes, int n_in,
                              void* d_out, int out_size, void* d_ws, size_t ws_size,
                              hipStream_t stream) {
    const float* x  = (const float*)d_in[0];
    const float* wg = (const float*)d_in[1];
    // d_in[2] = gating_t: sigmoid(x/temp) is monotonic -> argmax unaffected
    float* out = (float*)d_out;

    k_prep<<<NE, 256, 0, stream>>>(wg);
    k_gemm<<<NT / BMT, 256, 0, stream>>>(x);
    k_fix<<<2048, 64, 0, stream>>>(x);
    k_scan<<<1, 512, 0, stream>>>(out);
    k_place<<<256, 64, 0, stream>>>(out);
}